// Round 1
// baseline (639.337 us; speedup 1.0000x reference)
//
#include <hip/hip_runtime.h>

#define HID 16
#define NFEAT 512

__global__ __launch_bounds__(256) void init_deg(float* deg, int n) {
    int i = blockIdx.x * 256 + threadIdx.x;
    if (i < n) deg[i] = 1.0f;
}

__global__ __launch_bounds__(256) void deg_count(const int* __restrict__ dst, float* deg, int e) {
    int i = blockIdx.x * 256 + threadIdx.x;
    if (i < e) atomicAdd(&deg[dst[i]], 1.0f);
}

__global__ __launch_bounds__(256) void deg_rsqrt(float* deg, int n) {
    int i = blockIdx.x * 256 + threadIdx.x;
    if (i < n) deg[i] = rsqrtf(deg[i]);
}

// h1 = x @ W1   (x: [n,512], W1: [512,16])
// 16 threads per row (one per output feature), W1 staged in LDS.
__global__ __launch_bounds__(256) void mm1(const float* __restrict__ x,
                                           const float* __restrict__ W1,
                                           float* __restrict__ h1, int n) {
    __shared__ float W1s[NFEAT * HID];
    for (int i = threadIdx.x; i < NFEAT * HID / 4; i += 256)
        ((float4*)W1s)[i] = ((const float4*)W1)[i];
    __syncthreads();

    int j = threadIdx.x & 15;          // output feature
    int r = threadIdx.x >> 4;          // row within block (0..15)
    int row = blockIdx.x * 16 + r;
    if (row >= n) return;

    const float4* xr = (const float4*)(x + (size_t)row * NFEAT);
    float acc = 0.f;
#pragma unroll 8
    for (int k4 = 0; k4 < NFEAT / 4; ++k4) {
        float4 xv = xr[k4];
        int k = k4 * 4;
        acc += xv.x * W1s[(k + 0) * HID + j];
        acc += xv.y * W1s[(k + 1) * HID + j];
        acc += xv.z * W1s[(k + 2) * HID + j];
        acc += xv.w * W1s[(k + 3) * HID + j];
    }
    h1[(size_t)row * HID + j] = acc;
}

// agg[dst] += h[src] * dis[src]*dis[dst]   — one thread per (edge, feature)
__global__ __launch_bounds__(256) void prop(const int* __restrict__ src,
                                            const int* __restrict__ dst,
                                            const float* __restrict__ dis,
                                            const float* __restrict__ h,
                                            float* __restrict__ agg, int e) {
    int idx = blockIdx.x * 256 + threadIdx.x;   // e*16 = 51.2M < 2^31
    int ed = idx >> 4, j = idx & 15;
    if (ed >= e) return;
    int s = src[ed], d = dst[ed];
    float w = dis[s] * dis[d];
    atomicAdd(&agg[(size_t)d * HID + j], h[(size_t)s * HID + j] * w);
}

// h = relu(agg1 + h1*dis^2 + b1);  h2 = h @ W2 (16x16 via intra-16-lane shuffles);
// writes h2 over h1.
__global__ __launch_bounds__(256) void mid(const float* __restrict__ agg1,
                                           float* __restrict__ h1,
                                           const float* __restrict__ dis,
                                           const float* __restrict__ b1,
                                           const float* __restrict__ W2, int n) {
    __shared__ float W2s[HID * HID];
    if (threadIdx.x < HID * HID) W2s[threadIdx.x] = W2[threadIdx.x];
    __syncthreads();

    int idx = blockIdx.x * 256 + threadIdx.x;   // = nrow*16 + j
    int nrow = idx >> 4, j = idx & 15;
    if (nrow >= n) return;
    float dn = dis[nrow];
    float a = agg1[idx] + h1[idx] * dn * dn + b1[j];
    float hv = fmaxf(a, 0.f);
    float h2 = 0.f;
#pragma unroll
    for (int k = 0; k < HID; ++k)
        h2 += __shfl(hv, k, HID) * W2s[k * HID + j];
    h1[idx] = h2;
}

// z = agg2 + h2*dis^2 + b2;  out = z + eps*exp(0.5*z)   (agg2 accumulated in d_out)
__global__ __launch_bounds__(256) void finalk(float* __restrict__ out,
                                              const float* __restrict__ h2,
                                              const float* __restrict__ dis,
                                              const float* __restrict__ b2,
                                              const float* __restrict__ eps, int n) {
    int idx = blockIdx.x * 256 + threadIdx.x;
    int nrow = idx >> 4, j = idx & 15;
    if (nrow >= n) return;
    float dn = dis[nrow];
    float z = out[idx] + h2[idx] * dn * dn + b2[j];
    out[idx] = z + eps[idx] * expf(0.5f * z);
}

extern "C" void kernel_launch(void* const* d_in, const int* in_sizes, int n_in,
                              void* d_out, int out_size, void* d_ws, size_t ws_size,
                              hipStream_t stream) {
    const float* x   = (const float*)d_in[0];
    const float* W1  = (const float*)d_in[1];
    const float* b1  = (const float*)d_in[2];
    const float* W2  = (const float*)d_in[3];
    const float* b2  = (const float*)d_in[4];
    const float* eps = (const float*)d_in[5];
    const int*   ei  = (const int*)d_in[6];

    int n = in_sizes[5] / HID;   // 100000
    int e = in_sizes[6] / 2;     // 3200000
    const int* srcs = ei;
    const int* dsts = ei + e;

    float* ws   = (float*)d_ws;
    float* dis  = ws;                             // n floats (deg -> rsqrt in place)
    float* h1   = ws + n;                         // n*HID (later h2)
    float* agg1 = ws + n + (size_t)n * HID;       // n*HID
    float* outf = (float*)d_out;                  // layer-2 accumulator, then final

    size_t featBytes = (size_t)n * HID * sizeof(float);
    hipMemsetAsync(agg1, 0, featBytes, stream);
    hipMemsetAsync(outf, 0, featBytes, stream);

    int nBlk = (n + 255) / 256;
    init_deg<<<nBlk, 256, 0, stream>>>(dis, n);
    deg_count<<<(e + 255) / 256, 256, 0, stream>>>(dsts, dis, e);
    deg_rsqrt<<<nBlk, 256, 0, stream>>>(dis, n);

    mm1<<<(n + 15) / 16, 256, 0, stream>>>(x, W1, h1, n);

    int propBlocks = (e * 16 + 255) / 256;        // 200000
    prop<<<propBlocks, 256, 0, stream>>>(srcs, dsts, dis, h1, agg1, e);

    int featBlocks = (n * 16 + 255) / 256;        // 6250
    mid<<<featBlocks, 256, 0, stream>>>(agg1, h1, dis, b1, W2, n);

    prop<<<propBlocks, 256, 0, stream>>>(srcs, dsts, dis, h1, outf, e);

    finalk<<<featBlocks, 256, 0, stream>>>(outf, h1, dis, b2, eps, n);
}